// Round 1
// baseline (612.132 us; speedup 1.0000x reference)
//
#include <hip/hip_runtime.h>
#include <cmath>

constexpr int BB = 4, CC = 64, HH = 256, WW = 256;
constexpr int WP = 258;   // padded width: cols -1..256 stored at col+1
constexpr int C2R = 257;  // c2 rows -1..255 stored at r+1

typedef short short8 __attribute__((ext_vector_type(8)));
typedef float f32x4 __attribute__((ext_vector_type(4)));
#define MFMA_BF16 __builtin_amdgcn_mfma_f32_16x16x32_bf16

union U16x8 { uint4 v; unsigned short h[8]; };
union U16x4 { uint2 v; unsigned short h[4]; };

__device__ inline unsigned short f2bf(float f) {
  unsigned u = __builtin_bit_cast(unsigned, f);
  u += 0x7fffu + ((u >> 16) & 1u);
  return (unsigned short)(u >> 16);
}
__device__ inline unsigned short f2bf_trunc(float f) {
  return (unsigned short)(__builtin_bit_cast(unsigned, f) >> 16);
}
__device__ inline float bf2f(unsigned short h) {
  unsigned u = ((unsigned)h) << 16;
  return __builtin_bit_cast(float, u);
}

// ---------------------------------------------------------------------------
// k_pack: block = half-row (128 px). NCHW fp32 -> col-padded NHWC bf16 +
// fused channel-max -> s. (unchanged, passing)
// ---------------------------------------------------------------------------
__global__ __launch_bounds__(256, 4) void k_pack(const float* __restrict__ x,
                                                 float* __restrict__ s,
                                                 unsigned short* __restrict__ xn) {
  __shared__ float tile[CC * 129];
  __shared__ float pmax[2][128];
  const int t = threadIdx.x;
  const int half = blockIdx.x & 1, y = blockIdx.x >> 1, b = blockIdx.y;
  const int px0 = half * 128;
  const int pxl = t & 127, chb = (t >> 7) * 32;

  const float* base = x + (size_t)b * CC * HH * WW + (size_t)y * WW + px0 + pxl;
  float m = -1e30f;
#pragma unroll 8
  for (int i = 0; i < 32; ++i) {
    float v = base[(size_t)(chb + i) * HH * WW];
    tile[(chb + i) * 129 + pxl] = v;
    m = fmaxf(m, v);
  }
  pmax[t >> 7][pxl] = m;

  uint4* xn4 = (uint4*)xn;
  if (t < 8) {
    int col = half ? (WP - 1) : 0;
    xn4[(((size_t)(b * HH + y) * WP + col) * CC + t * 8) >> 3] =
        make_uint4(0, 0, 0, 0);
  }
  __syncthreads();

  if (t < 128) {
    float mm = fmaxf(pmax[0][t], pmax[1][t]);
    s[(b * HH + y) * WW + px0 + t] = 25.0f / fminf(fmaxf(mm, 1.0f), 50.0f);
  }
#pragma unroll
  for (int g = 0; g < 4; ++g) {
    int px = g * 32 + (t >> 3), c8 = t & 7;
    U16x8 r;
#pragma unroll
    for (int j = 0; j < 8; ++j) r.h[j] = f2bf(tile[(c8 * 8 + j) * 129 + px]);
    xn4[(((size_t)(b * HH + y) * WP + px0 + px + 1) * CC + c8 * 8) >> 3] = r.v;
  }
}

// ---------------------------------------------------------------------------
// k_wpack: W fp32 -> bf16 fragments Wp[tap][mt][kc][lane][8]   (unchanged)
// ---------------------------------------------------------------------------
__global__ __launch_bounds__(256) void k_wpack(const float* __restrict__ Wt,
                                               unsigned short* __restrict__ Wp) {
  int gid = blockIdx.x * 256 + threadIdx.x;  // 4608 total
  int lane = gid & 63, kc = (gid >> 6) & 1, mt = (gid >> 7) & 3, tap = gid >> 9;
  int o = mt * 16 + (lane & 15);
  int kb = kc * 32 + (lane >> 4) * 8;
  int ky = tap / 3, kx = tap % 3;
  U16x8 r;
#pragma unroll
  for (int j = 0; j < 8; ++j)
    r.h[j] = f2bf(Wt[o * 576 + (kb + j) * 9 + ky * 3 + kx]);
  ((uint4*)Wp)[gid] = r.v;
}

// ---------------------------------------------------------------------------
// Conv tile: block = 2 out rows x 64 cols x 64 och.
// kc-SPLIT staging: one 4 rows x 66 cols x 4 chunk(8ch) uint4 buffer = 16.9 KB
// reused for both 32-channel halves -> 8 blocks/CU, 32 waves/CU (was 4/16).
// Schedule: stage(kc0) sync mfma(kc0) sync stage(kc1) sync mfma(kc1) epilogue.
// 4-chunk swizzle: slot = q ^ ((col>>1)&3); read chunk' = quad ^ ((col>>1)&3)
// -> a 16-lane b128 read group covers all 8 bank-groups (2-way, free).
// ---------------------------------------------------------------------------
__global__ __launch_bounds__(256, 8) void k_lower(const unsigned short* __restrict__ xn,
                                                  const unsigned short* __restrict__ Wp,
                                                  const float* __restrict__ s,
                                                  unsigned short* __restrict__ c2) {
  __shared__ uint4 lds[1056];
  const int t = threadIdx.x;
  const int ctile = blockIdx.x & 3, tr = blockIdx.x >> 2;
  const int b = blockIdx.y;
  const int r0 = tr * 2 - 1;          // out rows r0, r0+1 in [-1, 256]
  const int colBase = ctile * 64;

  const int lane = t & 63, w = t >> 6;
  const int ow = w & 1, ch2 = w >> 1;
  const int quad = lane >> 4, l15 = lane & 15;
  const uint4* wp4 = (const uint4*)Wp;
  const uint4* xn4 = (const uint4*)xn;

  f32x4 acc[2][2][2];  // [pt][rr][ct]
#pragma unroll
  for (int pt = 0; pt < 2; ++pt)
#pragma unroll
    for (int rr = 0; rr < 2; ++rr)
#pragma unroll
      for (int ct = 0; ct < 2; ++ct) acc[pt][rr][ct] = {0.f, 0.f, 0.f, 0.f};

#pragma unroll 1
  for (int kc = 0; kc < 2; ++kc) {
    // ---- stage this kc's 32-channel half: 1056 uint4, blended on the fly
#pragma unroll
    for (int g = 0; g < 2; ++g) {
      const int nj = g ? 2 : 3;   // batches of 3 + 2 (compile-time after unroll)
      float w0a[3], w1a[3];
      int o0a[3], o1a[3], la[3];
      bool act[3], va[3];
#pragma unroll
      for (int j = 0; j < 3; ++j) {
        if (j >= nj) break;
        int idx = (g * 3 + j) * 256 + t;
        act[j] = idx < 1056;
        int rr_ = idx / 264, rem = idx % 264;  // 264 = 66 cols * 4 chunks
        int col_ = rem >> 2, ch_ = rem & 3;
        int xrow = r0 - 1 + rr_;  // x2 row, [-2..258]
        va[j] = act[j] && (xrow >= 0) && (xrow < HH);
        la[j] = (rr_ * 66 + col_) * 4 + (ch_ ^ ((col_ >> 1) & 3));
        float sv = 0.0f;
        int pxc = min(max(colBase + col_ - 1, 0), WW - 1);
        if (va[j]) sv = s[(b * HH + min(max(xrow, 0), HH - 1)) * WW + pxc];
        float ys = (float)xrow - sv;
        float fy = floorf(ys);
        float wfr = ys - fy;
        int i0 = (int)fy;
        w0a[j] = (i0 >= 0) ? 1.0f - wfr : 0.0f;
        w1a[j] = (i0 + 1 >= 0) ? wfr : 0.0f;
        int a0 = min(max(i0, 0), HH - 1), a1 = min(max(i0 + 1, 0), HH - 1);
        o0a[j] = ((b * HH + a0) * WP + colBase + col_) * 8 + kc * 4 + ch_;
        o1a[j] = ((b * HH + a1) * WP + colBase + col_) * 8 + kc * 4 + ch_;
      }
#pragma unroll
      for (int j = 0; j < 3; ++j) {
        if (j >= nj) break;
        if (act[j]) {
          uint4 v = make_uint4(0, 0, 0, 0);
          if (va[j]) {
            U16x8 u0, u1, rr;
            u0.v = xn4[o0a[j]];
            u1.v = xn4[o1a[j]];
#pragma unroll
            for (int k = 0; k < 8; ++k)
              rr.h[k] = f2bf_trunc(w0a[j] * bf2f(u0.h[k]) + w1a[j] * bf2f(u1.h[k]));
            v = rr.v;
          }
          lds[la[j]] = v;
        }
      }
    }
    __syncthreads();

    short8 wf[9][2];
#pragma unroll
    for (int tap = 0; tap < 9; ++tap)
#pragma unroll
      for (int ct = 0; ct < 2; ++ct)
        wf[tap][ct] = __builtin_bit_cast(
            short8, wp4[((tap * 4 + (ow * 2 + ct)) * 2 + kc) * 64 + lane]);
#pragma unroll
    for (int pt = 0; pt < 2; ++pt) {
#pragma unroll
      for (int ir = 0; ir < 4; ++ir) {
#pragma unroll
        for (int kx = 0; kx < 3; ++kx) {
          int col = ch2 * 32 + pt * 16 + l15 + kx;
          short8 xf = __builtin_bit_cast(
              short8, lds[(ir * 66 + col) * 4 + (quad ^ ((col >> 1) & 3))]);
          if (ir <= 2) {
#pragma unroll
            for (int ct = 0; ct < 2; ++ct)
              acc[pt][0][ct] = MFMA_BF16(wf[ir * 3 + kx][ct], xf, acc[pt][0][ct], 0, 0, 0);
          }
          if (ir >= 1) {
#pragma unroll
            for (int ct = 0; ct < 2; ++ct)
              acc[pt][1][ct] = MFMA_BF16(wf[(ir - 1) * 3 + kx][ct], xf, acc[pt][1][ct], 0, 0, 0);
          }
        }
      }
    }
    __syncthreads();  // buffer reuse guard before next kc's staging
  }

  uint2* c2u = (uint2*)c2;
#pragma unroll
  for (int pt = 0; pt < 2; ++pt) {
    int px = colBase + ch2 * 32 + pt * 16 + l15;
#pragma unroll
    for (int rr = 0; rr < 2; ++rr) {
      int r = r0 + rr;
      if (r > 255) continue;
#pragma unroll
      for (int ct = 0; ct < 2; ++ct) {
        f32x4 A = acc[pt][rr][ct];
        int og = (ow * 2 + ct) * 4 + quad;
        unsigned short h0 = f2bf(A[0]), h1 = f2bf(A[1]), h2 = f2bf(A[2]), h3 = f2bf(A[3]);
        uint2 val = make_uint2((unsigned)h0 | ((unsigned)h1 << 16),
                               (unsigned)h2 | ((unsigned)h3 << 16));
        c2u[(size_t)((b * 16 + og) * C2R + (r + 1)) * WW + px] = val;
      }
    }
  }
}

// ---------------------------------------------------------------------------
// k_final: out rows y0, y0+1. Same kc-split tile (16.9 KB, 8 blocks/CU);
// epilogue s-loads hoisted to kernel start; epilogue resamples c2 + min ->
// out NCHW fp32.
// ---------------------------------------------------------------------------
__global__ __launch_bounds__(256, 8) void k_final(const unsigned short* __restrict__ xn,
                                                  const unsigned short* __restrict__ Wp,
                                                  const float* __restrict__ s,
                                                  const unsigned short* __restrict__ c2,
                                                  float* __restrict__ out) {
  __shared__ uint4 lds[1056];
  const int t = threadIdx.x;
  const int ctile = blockIdx.x & 3, tr = blockIdx.x >> 2;
  const int b = blockIdx.y;
  const int y0 = tr * 2;
  const int colBase = ctile * 64;

  const int lane = t & 63, w = t >> 6;
  const int ow = w & 1, ch2 = w >> 1;
  const int quad = lane >> 4, l15 = lane & 15;
  const uint4* src4 = (const uint4*)xn;
  const uint4* wp4 = (const uint4*)Wp;

  // hoisted epilogue s-loads: issue before staging, consumed after MFMA
  float sv_e[2][2];
#pragma unroll
  for (int pt = 0; pt < 2; ++pt)
#pragma unroll
    for (int rr = 0; rr < 2; ++rr)
      sv_e[pt][rr] =
          s[(b * HH + (y0 + rr)) * WW + (colBase + ch2 * 32 + pt * 16 + l15)];

  f32x4 acc[2][2][2];
#pragma unroll
  for (int pt = 0; pt < 2; ++pt)
#pragma unroll
    for (int rr = 0; rr < 2; ++rr)
#pragma unroll
      for (int ct = 0; ct < 2; ++ct) acc[pt][rr][ct] = {0.f, 0.f, 0.f, 0.f};

#pragma unroll 1
  for (int kc = 0; kc < 2; ++kc) {
    // ---- stage this kc's half: straight copy, 5 fully-unrolled iterations
#pragma unroll
    for (int i = 0; i < 5; ++i) {
      int idx = i * 256 + t;
      if (idx < 1056) {
        int rr_ = idx / 264, rem = idx % 264;
        int col_ = rem >> 2, ch_ = rem & 3;
        int xrow = y0 - 1 + rr_;  // rows y0-1 .. y0+2
        uint4 v = make_uint4(0, 0, 0, 0);
        if (xrow >= 0 && xrow < HH)
          v = src4[((size_t)(b * HH + xrow) * WP + colBase + col_) * 8 + kc * 4 + ch_];
        lds[(rr_ * 66 + col_) * 4 + (ch_ ^ ((col_ >> 1) & 3))] = v;
      }
    }
    __syncthreads();

    short8 wf[9][2];
#pragma unroll
    for (int tap = 0; tap < 9; ++tap)
#pragma unroll
      for (int ct = 0; ct < 2; ++ct)
        wf[tap][ct] = __builtin_bit_cast(
            short8, wp4[((tap * 4 + (ow * 2 + ct)) * 2 + kc) * 64 + lane]);
#pragma unroll
    for (int pt = 0; pt < 2; ++pt) {
#pragma unroll
      for (int ir = 0; ir < 4; ++ir) {
#pragma unroll
        for (int kx = 0; kx < 3; ++kx) {
          int col = ch2 * 32 + pt * 16 + l15 + kx;
          short8 xf = __builtin_bit_cast(
              short8, lds[(ir * 66 + col) * 4 + (quad ^ ((col >> 1) & 3))]);
          if (ir <= 2) {
#pragma unroll
            for (int ct = 0; ct < 2; ++ct)
              acc[pt][0][ct] = MFMA_BF16(wf[ir * 3 + kx][ct], xf, acc[pt][0][ct], 0, 0, 0);
          }
          if (ir >= 1) {
#pragma unroll
            for (int ct = 0; ct < 2; ++ct)
              acc[pt][1][ct] = MFMA_BF16(wf[(ir - 1) * 3 + kx][ct], xf, acc[pt][1][ct], 0, 0, 0);
          }
        }
      }
    }
    __syncthreads();  // buffer reuse guard before next kc's staging
  }

  const uint2* c2u = (const uint2*)c2;
#pragma unroll
  for (int pt = 0; pt < 2; ++pt) {
    int px = colBase + ch2 * 32 + pt * 16 + l15;
#pragma unroll
    for (int rr = 0; rr < 2; ++rr) {
      int y = y0 + rr;
      float sv = sv_e[pt][rr];
      float ys = (float)y - sv;
      float fy = floorf(ys);
      float wfr = ys - fy;
      int i0 = (int)fy;
      float lw0 = (i0 + 1 >= 0 && i0 + 1 <= HH) ? 1.0f - wfr : 0.0f;
      float lw1 = (i0 + 2 >= 0 && i0 + 2 <= HH) ? wfr : 0.0f;
      int a0 = min(max(i0 + 1, 0), HH);
      int a1 = min(max(i0 + 2, 0), HH);
#pragma unroll
      for (int ct = 0; ct < 2; ++ct) {
        f32x4 A = acc[pt][rr][ct];
        int og = (ow * 2 + ct) * 4 + quad;
        U16x4 v0, v1;
        v0.v = c2u[(size_t)((b * 16 + og) * C2R + a0) * WW + px];
        v1.v = c2u[(size_t)((b * 16 + og) * C2R + a1) * WW + px];
#pragma unroll
        for (int reg = 0; reg < 4; ++reg) {
          float lower = lw0 * bf2f(v0.h[reg]) + lw1 * bf2f(v1.h[reg]);
          out[((size_t)(b * CC + og * 4 + reg) * HH + y) * WW + px] =
              fminf(A[reg], lower);
        }
      }
    }
  }
}

// ---------------------------------------------------------------------------
extern "C" void kernel_launch(void* const* d_in, const int* in_sizes, int n_in,
                              void* d_out, int out_size, void* d_ws, size_t ws_size,
                              hipStream_t stream) {
  const float* x = (const float*)d_in[0];
  const float* Wt = (const float*)d_in[1];
  float* out = (float*)d_out;

  char* ws = (char*)d_ws;
  float* s = (float*)ws;                                   //   1,048,576 B
  unsigned short* Wp = (unsigned short*)(ws + 1048576);    //      73,728 B
  unsigned short* xn = (unsigned short*)(ws + 1122304);    //  33,816,576 B
  unsigned short* c2 = (unsigned short*)(ws + 34938880);   //  33,685,504 B
                                                           // total 68.6 MB
  k_pack<<<dim3(HH * 2, BB), 256, 0, stream>>>(x, s, xn);
  k_wpack<<<dim3(18), 256, 0, stream>>>(Wt, Wp);
  k_lower<<<dim3(4 * 129, BB), 256, 0, stream>>>(xn, Wp, s, c2);
  k_final<<<dim3(4 * 128, BB), 256, 0, stream>>>(xn, Wp, s, c2, out);
}

// Round 2
// 245.609 us; speedup vs baseline: 2.4923x; 2.4923x over previous
//
#include <hip/hip_runtime.h>
#include <cmath>

constexpr int BB = 4, CC = 64, HH = 256, WW = 256;
constexpr int WP = 258;   // padded width: cols -1..256 stored at col+1
constexpr int C2R = 257;  // c2 rows -1..255 stored at r+1

typedef short short8 __attribute__((ext_vector_type(8)));
typedef float f32x4 __attribute__((ext_vector_type(4)));
#define MFMA_BF16 __builtin_amdgcn_mfma_f32_16x16x32_bf16

union U16x8 { uint4 v; unsigned short h[8]; };
union U16x4 { uint2 v; unsigned short h[4]; };

__device__ inline unsigned short f2bf(float f) {
  unsigned u = __builtin_bit_cast(unsigned, f);
  u += 0x7fffu + ((u >> 16) & 1u);
  return (unsigned short)(u >> 16);
}
__device__ inline unsigned short f2bf_trunc(float f) {
  return (unsigned short)(__builtin_bit_cast(unsigned, f) >> 16);
}
__device__ inline float bf2f(unsigned short h) {
  unsigned u = ((unsigned)h) << 16;
  return __builtin_bit_cast(float, u);
}

// ---------------------------------------------------------------------------
// k_pack: block = half-row (128 px). NCHW fp32 -> col-padded NHWC bf16 +
// fused channel-max -> s. (unchanged, passing)
// ---------------------------------------------------------------------------
__global__ __launch_bounds__(256, 4) void k_pack(const float* __restrict__ x,
                                                 float* __restrict__ s,
                                                 unsigned short* __restrict__ xn) {
  __shared__ float tile[CC * 129];
  __shared__ float pmax[2][128];
  const int t = threadIdx.x;
  const int half = blockIdx.x & 1, y = blockIdx.x >> 1, b = blockIdx.y;
  const int px0 = half * 128;
  const int pxl = t & 127, chb = (t >> 7) * 32;

  const float* base = x + (size_t)b * CC * HH * WW + (size_t)y * WW + px0 + pxl;
  float m = -1e30f;
#pragma unroll 8
  for (int i = 0; i < 32; ++i) {
    float v = base[(size_t)(chb + i) * HH * WW];
    tile[(chb + i) * 129 + pxl] = v;
    m = fmaxf(m, v);
  }
  pmax[t >> 7][pxl] = m;

  uint4* xn4 = (uint4*)xn;
  if (t < 8) {
    int col = half ? (WP - 1) : 0;
    xn4[(((size_t)(b * HH + y) * WP + col) * CC + t * 8) >> 3] =
        make_uint4(0, 0, 0, 0);
  }
  __syncthreads();

  if (t < 128) {
    float mm = fmaxf(pmax[0][t], pmax[1][t]);
    s[(b * HH + y) * WW + px0 + t] = 25.0f / fminf(fmaxf(mm, 1.0f), 50.0f);
  }
#pragma unroll
  for (int g = 0; g < 4; ++g) {
    int px = g * 32 + (t >> 3), c8 = t & 7;
    U16x8 r;
#pragma unroll
    for (int j = 0; j < 8; ++j) r.h[j] = f2bf(tile[(c8 * 8 + j) * 129 + px]);
    xn4[(((size_t)(b * HH + y) * WP + px0 + px + 1) * CC + c8 * 8) >> 3] = r.v;
  }
}

// ---------------------------------------------------------------------------
// k_wpack: W fp32 -> bf16 fragments Wp[tap][mt][kc][lane][8]   (unchanged)
// ---------------------------------------------------------------------------
__global__ __launch_bounds__(256) void k_wpack(const float* __restrict__ Wt,
                                               unsigned short* __restrict__ Wp) {
  int gid = blockIdx.x * 256 + threadIdx.x;  // 4608 total
  int lane = gid & 63, kc = (gid >> 6) & 1, mt = (gid >> 7) & 3, tap = gid >> 9;
  int o = mt * 16 + (lane & 15);
  int kb = kc * 32 + (lane >> 4) * 8;
  int ky = tap / 3, kx = tap % 3;
  U16x8 r;
#pragma unroll
  for (int j = 0; j < 8; ++j)
    r.h[j] = f2bf(Wt[o * 576 + (kb + j) * 9 + ky * 3 + kx]);
  ((uint4*)Wp)[gid] = r.v;
}

// ---------------------------------------------------------------------------
// Conv tile: block = 2 out rows x 64 cols x 64 och.
// kc-SPLIT staging: one 4 rows x 66 cols x 4 chunk(8ch) uint4 buffer = 16.9 KB
// reused for both 32-channel halves. LDS allows 9 blocks/CU; with VGPR<=64
// (compiler picked 52 under (256,4) for this loop) HW allows 8 waves/SIMD ->
// natural 8 blocks/CU, NO register cap (the (256,8) cap spilled: 850 MB/disp
// scratch traffic, R1 post-mortem).
// Schedule: stage(kc0) sync mfma(kc0) sync stage(kc1) sync mfma(kc1) epilogue.
// 4-chunk swizzle: slot = ch ^ ((col>>1)&3); read chunk' = quad ^ ((col>>1)&3)
// -> a 16-lane b128 read group covers all 8 bank-groups (2-way, free).
// ---------------------------------------------------------------------------
__global__ __launch_bounds__(256, 4) void k_lower(const unsigned short* __restrict__ xn,
                                                  const unsigned short* __restrict__ Wp,
                                                  const float* __restrict__ s,
                                                  unsigned short* __restrict__ c2) {
  __shared__ uint4 lds[1056];
  const int t = threadIdx.x;
  const int ctile = blockIdx.x & 3, tr = blockIdx.x >> 2;
  const int b = blockIdx.y;
  const int r0 = tr * 2 - 1;          // out rows r0, r0+1 in [-1, 256]
  const int colBase = ctile * 64;

  const int lane = t & 63, w = t >> 6;
  const int ow = w & 1, ch2 = w >> 1;
  const int quad = lane >> 4, l15 = lane & 15;
  const uint4* wp4 = (const uint4*)Wp;
  const uint4* xn4 = (const uint4*)xn;

  f32x4 acc[2][2][2];  // [pt][rr][ct]
#pragma unroll
  for (int pt = 0; pt < 2; ++pt)
#pragma unroll
    for (int rr = 0; rr < 2; ++rr)
#pragma unroll
      for (int ct = 0; ct < 2; ++ct) acc[pt][rr][ct] = {0.f, 0.f, 0.f, 0.f};

#pragma unroll 1
  for (int kc = 0; kc < 2; ++kc) {
    // ---- stage this kc's 32-channel half: 1056 uint4, blended on the fly
#pragma unroll
    for (int g = 0; g < 2; ++g) {
      const int nj = g ? 2 : 3;   // batches of 3 + 2 (compile-time after unroll)
      float w0a[3], w1a[3];
      int o0a[3], o1a[3], la[3];
      bool act[3], va[3];
#pragma unroll
      for (int j = 0; j < 3; ++j) {
        if (j >= nj) break;
        int idx = (g * 3 + j) * 256 + t;
        act[j] = idx < 1056;
        int rr_ = idx / 264, rem = idx % 264;  // 264 = 66 cols * 4 chunks
        int col_ = rem >> 2, ch_ = rem & 3;
        int xrow = r0 - 1 + rr_;  // x2 row, [-2..258]
        va[j] = act[j] && (xrow >= 0) && (xrow < HH);
        la[j] = (rr_ * 66 + col_) * 4 + (ch_ ^ ((col_ >> 1) & 3));
        float sv = 0.0f;
        int pxc = min(max(colBase + col_ - 1, 0), WW - 1);
        if (va[j]) sv = s[(b * HH + min(max(xrow, 0), HH - 1)) * WW + pxc];
        float ys = (float)xrow - sv;
        float fy = floorf(ys);
        float wfr = ys - fy;
        int i0 = (int)fy;
        w0a[j] = (i0 >= 0) ? 1.0f - wfr : 0.0f;
        w1a[j] = (i0 + 1 >= 0) ? wfr : 0.0f;
        int a0 = min(max(i0, 0), HH - 1), a1 = min(max(i0 + 1, 0), HH - 1);
        o0a[j] = ((b * HH + a0) * WP + colBase + col_) * 8 + kc * 4 + ch_;
        o1a[j] = ((b * HH + a1) * WP + colBase + col_) * 8 + kc * 4 + ch_;
      }
#pragma unroll
      for (int j = 0; j < 3; ++j) {
        if (j >= nj) break;
        if (act[j]) {
          uint4 v = make_uint4(0, 0, 0, 0);
          if (va[j]) {
            U16x8 u0, u1, rr;
            u0.v = xn4[o0a[j]];
            u1.v = xn4[o1a[j]];
#pragma unroll
            for (int k = 0; k < 8; ++k)
              rr.h[k] = f2bf_trunc(w0a[j] * bf2f(u0.h[k]) + w1a[j] * bf2f(u1.h[k]));
            v = rr.v;
          }
          lds[la[j]] = v;
        }
      }
    }
    __syncthreads();

    short8 wf[9][2];
#pragma unroll
    for (int tap = 0; tap < 9; ++tap)
#pragma unroll
      for (int ct = 0; ct < 2; ++ct)
        wf[tap][ct] = __builtin_bit_cast(
            short8, wp4[((tap * 4 + (ow * 2 + ct)) * 2 + kc) * 64 + lane]);
#pragma unroll
    for (int pt = 0; pt < 2; ++pt) {
#pragma unroll
      for (int ir = 0; ir < 4; ++ir) {
#pragma unroll
        for (int kx = 0; kx < 3; ++kx) {
          int col = ch2 * 32 + pt * 16 + l15 + kx;
          short8 xf = __builtin_bit_cast(
              short8, lds[(ir * 66 + col) * 4 + (quad ^ ((col >> 1) & 3))]);
          if (ir <= 2) {
#pragma unroll
            for (int ct = 0; ct < 2; ++ct)
              acc[pt][0][ct] = MFMA_BF16(wf[ir * 3 + kx][ct], xf, acc[pt][0][ct], 0, 0, 0);
          }
          if (ir >= 1) {
#pragma unroll
            for (int ct = 0; ct < 2; ++ct)
              acc[pt][1][ct] = MFMA_BF16(wf[(ir - 1) * 3 + kx][ct], xf, acc[pt][1][ct], 0, 0, 0);
          }
        }
      }
    }
    __syncthreads();  // buffer reuse guard before next kc's staging
  }

  uint2* c2u = (uint2*)c2;
#pragma unroll
  for (int pt = 0; pt < 2; ++pt) {
    int px = colBase + ch2 * 32 + pt * 16 + l15;
#pragma unroll
    for (int rr = 0; rr < 2; ++rr) {
      int r = r0 + rr;
      if (r > 255) continue;
#pragma unroll
      for (int ct = 0; ct < 2; ++ct) {
        f32x4 A = acc[pt][rr][ct];
        int og = (ow * 2 + ct) * 4 + quad;
        unsigned short h0 = f2bf(A[0]), h1 = f2bf(A[1]), h2 = f2bf(A[2]), h3 = f2bf(A[3]);
        uint2 val = make_uint2((unsigned)h0 | ((unsigned)h1 << 16),
                               (unsigned)h2 | ((unsigned)h3 << 16));
        c2u[(size_t)((b * 16 + og) * C2R + (r + 1)) * WW + px] = val;
      }
    }
  }
}

// ---------------------------------------------------------------------------
// k_final: out rows y0, y0+1. Same kc-split tile (16.9 KB);
// epilogue s-loads hoisted to kernel start; epilogue resamples c2 + min ->
// out NCHW fp32.
// ---------------------------------------------------------------------------
__global__ __launch_bounds__(256, 4) void k_final(const unsigned short* __restrict__ xn,
                                                  const unsigned short* __restrict__ Wp,
                                                  const float* __restrict__ s,
                                                  const unsigned short* __restrict__ c2,
                                                  float* __restrict__ out) {
  __shared__ uint4 lds[1056];
  const int t = threadIdx.x;
  const int ctile = blockIdx.x & 3, tr = blockIdx.x >> 2;
  const int b = blockIdx.y;
  const int y0 = tr * 2;
  const int colBase = ctile * 64;

  const int lane = t & 63, w = t >> 6;
  const int ow = w & 1, ch2 = w >> 1;
  const int quad = lane >> 4, l15 = lane & 15;
  const uint4* src4 = (const uint4*)xn;
  const uint4* wp4 = (const uint4*)Wp;

  // hoisted epilogue s-loads: issue before staging, consumed after MFMA
  float sv_e[2][2];
#pragma unroll
  for (int pt = 0; pt < 2; ++pt)
#pragma unroll
    for (int rr = 0; rr < 2; ++rr)
      sv_e[pt][rr] =
          s[(b * HH + (y0 + rr)) * WW + (colBase + ch2 * 32 + pt * 16 + l15)];

  f32x4 acc[2][2][2];
#pragma unroll
  for (int pt = 0; pt < 2; ++pt)
#pragma unroll
    for (int rr = 0; rr < 2; ++rr)
#pragma unroll
      for (int ct = 0; ct < 2; ++ct) acc[pt][rr][ct] = {0.f, 0.f, 0.f, 0.f};

#pragma unroll 1
  for (int kc = 0; kc < 2; ++kc) {
    // ---- stage this kc's half: straight copy, 5 fully-unrolled iterations
#pragma unroll
    for (int i = 0; i < 5; ++i) {
      int idx = i * 256 + t;
      if (idx < 1056) {
        int rr_ = idx / 264, rem = idx % 264;
        int col_ = rem >> 2, ch_ = rem & 3;
        int xrow = y0 - 1 + rr_;  // rows y0-1 .. y0+2
        uint4 v = make_uint4(0, 0, 0, 0);
        if (xrow >= 0 && xrow < HH)
          v = src4[((size_t)(b * HH + xrow) * WP + colBase + col_) * 8 + kc * 4 + ch_];
        lds[(rr_ * 66 + col_) * 4 + (ch_ ^ ((col_ >> 1) & 3))] = v;
      }
    }
    __syncthreads();

    short8 wf[9][2];
#pragma unroll
    for (int tap = 0; tap < 9; ++tap)
#pragma unroll
      for (int ct = 0; ct < 2; ++ct)
        wf[tap][ct] = __builtin_bit_cast(
            short8, wp4[((tap * 4 + (ow * 2 + ct)) * 2 + kc) * 64 + lane]);
#pragma unroll
    for (int pt = 0; pt < 2; ++pt) {
#pragma unroll
      for (int ir = 0; ir < 4; ++ir) {
#pragma unroll
        for (int kx = 0; kx < 3; ++kx) {
          int col = ch2 * 32 + pt * 16 + l15 + kx;
          short8 xf = __builtin_bit_cast(
              short8, lds[(ir * 66 + col) * 4 + (quad ^ ((col >> 1) & 3))]);
          if (ir <= 2) {
#pragma unroll
            for (int ct = 0; ct < 2; ++ct)
              acc[pt][0][ct] = MFMA_BF16(wf[ir * 3 + kx][ct], xf, acc[pt][0][ct], 0, 0, 0);
          }
          if (ir >= 1) {
#pragma unroll
            for (int ct = 0; ct < 2; ++ct)
              acc[pt][1][ct] = MFMA_BF16(wf[(ir - 1) * 3 + kx][ct], xf, acc[pt][1][ct], 0, 0, 0);
          }
        }
      }
    }
    __syncthreads();  // buffer reuse guard before next kc's staging
  }

  const uint2* c2u = (const uint2*)c2;
#pragma unroll
  for (int pt = 0; pt < 2; ++pt) {
    int px = colBase + ch2 * 32 + pt * 16 + l15;
#pragma unroll
    for (int rr = 0; rr < 2; ++rr) {
      int y = y0 + rr;
      float sv = sv_e[pt][rr];
      float ys = (float)y - sv;
      float fy = floorf(ys);
      float wfr = ys - fy;
      int i0 = (int)fy;
      float lw0 = (i0 + 1 >= 0 && i0 + 1 <= HH) ? 1.0f - wfr : 0.0f;
      float lw1 = (i0 + 2 >= 0 && i0 + 2 <= HH) ? wfr : 0.0f;
      int a0 = min(max(i0 + 1, 0), HH);
      int a1 = min(max(i0 + 2, 0), HH);
#pragma unroll
      for (int ct = 0; ct < 2; ++ct) {
        f32x4 A = acc[pt][rr][ct];
        int og = (ow * 2 + ct) * 4 + quad;
        U16x4 v0, v1;
        v0.v = c2u[(size_t)((b * 16 + og) * C2R + a0) * WW + px];
        v1.v = c2u[(size_t)((b * 16 + og) * C2R + a1) * WW + px];
#pragma unroll
        for (int reg = 0; reg < 4; ++reg) {
          float lower = lw0 * bf2f(v0.h[reg]) + lw1 * bf2f(v1.h[reg]);
          out[((size_t)(b * CC + og * 4 + reg) * HH + y) * WW + px] =
              fminf(A[reg], lower);
        }
      }
    }
  }
}

// ---------------------------------------------------------------------------
extern "C" void kernel_launch(void* const* d_in, const int* in_sizes, int n_in,
                              void* d_out, int out_size, void* d_ws, size_t ws_size,
                              hipStream_t stream) {
  const float* x = (const float*)d_in[0];
  const float* Wt = (const float*)d_in[1];
  float* out = (float*)d_out;

  char* ws = (char*)d_ws;
  float* s = (float*)ws;                                   //   1,048,576 B
  unsigned short* Wp = (unsigned short*)(ws + 1048576);    //      73,728 B
  unsigned short* xn = (unsigned short*)(ws + 1122304);    //  33,816,576 B
  unsigned short* c2 = (unsigned short*)(ws + 34938880);   //  33,685,504 B
                                                           // total 68.6 MB
  k_pack<<<dim3(HH * 2, BB), 256, 0, stream>>>(x, s, xn);
  k_wpack<<<dim3(18), 256, 0, stream>>>(Wt, Wp);
  k_lower<<<dim3(4 * 129, BB), 256, 0, stream>>>(xn, Wp, s, c2);
  k_final<<<dim3(4 * 128, BB), 256, 0, stream>>>(xn, Wp, s, c2, out);
}

// Round 3
// 187.901 us; speedup vs baseline: 3.2577x; 1.3071x over previous
//
#include <hip/hip_runtime.h>
#include <cmath>

constexpr int BB = 4, CC = 64, HH = 256, WW = 256;
constexpr int WP = 258;   // padded width: cols -1..256 stored at col+1
constexpr int C2R = 257;  // c2 rows -1..255 stored at r+1

typedef short short8 __attribute__((ext_vector_type(8)));
typedef float f32x4 __attribute__((ext_vector_type(4)));
#define MFMA_BF16 __builtin_amdgcn_mfma_f32_16x16x32_bf16

typedef __attribute__((address_space(1))) const unsigned gptr_t;
typedef __attribute__((address_space(3))) unsigned lptr_t;

union U16x8 { uint4 v; unsigned short h[8]; };
union U16x4 { uint2 v; unsigned short h[4]; };

__device__ inline unsigned short f2bf(float f) {
  unsigned u = __builtin_bit_cast(unsigned, f);
  u += 0x7fffu + ((u >> 16) & 1u);
  return (unsigned short)(u >> 16);
}
__device__ inline unsigned short f2bf_trunc(float f) {
  return (unsigned short)(__builtin_bit_cast(unsigned, f) >> 16);
}
__device__ inline float bf2f(unsigned short h) {
  unsigned u = ((unsigned)h) << 16;
  return __builtin_bit_cast(float, u);
}

// ---------------------------------------------------------------------------
// k_pack: block = half-row (128 px). NCHW fp32 -> col-padded NHWC bf16 +
// fused channel-max -> s. First 18 blocks of b=0 also do the weight pack
// (k_wpack folded in: one fewer launch).
// ---------------------------------------------------------------------------
__global__ __launch_bounds__(256, 4) void k_pack(const float* __restrict__ x,
                                                 const float* __restrict__ Wt,
                                                 float* __restrict__ s,
                                                 unsigned short* __restrict__ xn,
                                                 unsigned short* __restrict__ Wp) {
  __shared__ float tile[CC * 129];
  __shared__ float pmax[2][128];
  const int t = threadIdx.x;
  const int half = blockIdx.x & 1, y = blockIdx.x >> 1, b = blockIdx.y;
  const int px0 = half * 128;
  const int pxl = t & 127, chb = (t >> 7) * 32;

  // folded weight pack: Wp[tap][mt][kc][lane][8]
  if (b == 0 && blockIdx.x < 18) {
    int gid = blockIdx.x * 256 + t;  // 4608 total
    int lane = gid & 63, kc = (gid >> 6) & 1, mt = (gid >> 7) & 3, tap = gid >> 9;
    int o = mt * 16 + (lane & 15);
    int kb = kc * 32 + (lane >> 4) * 8;
    int ky = tap / 3, kx = tap % 3;
    U16x8 r;
#pragma unroll
    for (int j = 0; j < 8; ++j)
      r.h[j] = f2bf(Wt[o * 576 + (kb + j) * 9 + ky * 3 + kx]);
    ((uint4*)Wp)[gid] = r.v;
  }

  const float* base = x + (size_t)b * CC * HH * WW + (size_t)y * WW + px0 + pxl;
  float m = -1e30f;
#pragma unroll 8
  for (int i = 0; i < 32; ++i) {
    float v = base[(size_t)(chb + i) * HH * WW];
    tile[(chb + i) * 129 + pxl] = v;
    m = fmaxf(m, v);
  }
  pmax[t >> 7][pxl] = m;

  uint4* xn4 = (uint4*)xn;
  if (t < 8) {
    int col = half ? (WP - 1) : 0;
    xn4[(((size_t)(b * HH + y) * WP + col) * CC + t * 8) >> 3] =
        make_uint4(0, 0, 0, 0);
  }
  __syncthreads();

  if (t < 128) {
    float mm = fmaxf(pmax[0][t], pmax[1][t]);
    s[(b * HH + y) * WW + px0 + t] = 25.0f / fminf(fmaxf(mm, 1.0f), 50.0f);
  }
#pragma unroll
  for (int g = 0; g < 4; ++g) {
    int px = g * 32 + (t >> 3), c8 = t & 7;
    U16x8 r;
#pragma unroll
    for (int j = 0; j < 8; ++j) r.h[j] = f2bf(tile[(c8 * 8 + j) * 129 + px]);
    xn4[(((size_t)(b * HH + y) * WP + px0 + px + 1) * CC + c8 * 8) >> 3] = r.v;
  }
}

// ---------------------------------------------------------------------------
// Conv tile (round-0 structure: 33.8 KB LDS, ONE barrier, 4 blocks/CU).
// k_lower staging is software-pipelined: all 9 s-loads issued together,
// then gathers in 5+4 batches (10/8 uint4 in flight vs 3 before) -- the
// R2 post-mortem showed occupancy is register-capped at 4 waves/SIMD, so
// the fix is per-wave MLP, not residency.
// ---------------------------------------------------------------------------
__global__ __launch_bounds__(256, 4) void k_lower(const unsigned short* __restrict__ xn,
                                                  const unsigned short* __restrict__ Wp,
                                                  const float* __restrict__ s,
                                                  unsigned short* __restrict__ c2) {
  __shared__ uint4 lds[2112];
  const int t = threadIdx.x;
  const int ctile = blockIdx.x & 3, tr = blockIdx.x >> 2;
  const int b = blockIdx.y;
  const int r0 = tr * 2 - 1;          // out rows r0, r0+1 in [-1, 256]
  const int colBase = ctile * 64;

  const uint4* xn4 = (const uint4*)xn;

  // ---- phase 1: all 9 per-thread s-loads in flight together
  float sva[9];
#pragma unroll
  for (int j = 0; j < 9; ++j) {
    int idx = j * 256 + t;
    bool act = (j < 8) || (t < 64);
    int rr_ = idx / 528, rem = idx % 528;
    int col_ = rem >> 3;
    int xrow = r0 - 1 + rr_;  // x2 row, [-2..258]
    bool va = act && (xrow >= 0) && (xrow < HH);
    int pxc = min(max(colBase + col_ - 1, 0), WW - 1);
    sva[j] = va ? s[(b * HH + min(max(xrow, 0), HH - 1)) * WW + pxc] : 0.0f;
  }

  // ---- phase 2: gather+blend in 5+4 batches (loads clustered per batch)
#pragma unroll
  for (int h = 0; h < 2; ++h) {
    const int jb = h * 5;
    const int n = h ? 4 : 5;
    uint4 u0[5], u1[5];
    float w0a[5], w1a[5];
    int la[5];
    bool act[5], va[5];
#pragma unroll
    for (int j = 0; j < 5; ++j) {
      if (j >= n) break;
      const int e = jb + j;
      int idx = e * 256 + t;
      act[j] = (e < 8) || (t < 64);
      int rr_ = idx / 528, rem = idx % 528;
      int col_ = rem >> 3, ch_ = rem & 7;
      int xrow = r0 - 1 + rr_;
      va[j] = act[j] && (xrow >= 0) && (xrow < HH);
      la[j] = (rr_ * 66 + col_) * 8 + (ch_ ^ (col_ & 7));
      float ys = (float)xrow - sva[e];
      float fy = floorf(ys);
      float wfr = ys - fy;
      int i0 = (int)fy;
      w0a[j] = (i0 >= 0) ? 1.0f - wfr : 0.0f;
      w1a[j] = (i0 + 1 >= 0) ? wfr : 0.0f;
      int a0 = min(max(i0, 0), HH - 1), a1 = min(max(i0 + 1, 0), HH - 1);
      int o0 = ((b * HH + a0) * WP + colBase + col_) * 8 + ch_;
      int o1 = ((b * HH + a1) * WP + colBase + col_) * 8 + ch_;
      if (va[j]) {
        u0[j] = xn4[o0];
        u1[j] = xn4[o1];
      }
    }
#pragma unroll
    for (int j = 0; j < 5; ++j) {
      if (j >= n) break;
      if (act[j]) {
        uint4 v = make_uint4(0, 0, 0, 0);
        if (va[j]) {
          U16x8 a, bb, rr;
          a.v = u0[j];
          bb.v = u1[j];
#pragma unroll
          for (int k = 0; k < 8; ++k)
            rr.h[k] = f2bf_trunc(w0a[j] * bf2f(a.h[k]) + w1a[j] * bf2f(bb.h[k]));
          v = rr.v;
        }
        lds[la[j]] = v;
      }
    }
  }

  const int lane = t & 63, w = t >> 6;
  const int ow = w & 1, ch2 = w >> 1;
  const int quad = lane >> 4, l15 = lane & 15;
  const uint4* wp4 = (const uint4*)Wp;
  __syncthreads();

  f32x4 acc[2][2][2];  // [pt][rr][ct]
#pragma unroll
  for (int pt = 0; pt < 2; ++pt)
#pragma unroll
    for (int rr = 0; rr < 2; ++rr)
#pragma unroll
      for (int ct = 0; ct < 2; ++ct) acc[pt][rr][ct] = {0.f, 0.f, 0.f, 0.f};

#pragma unroll 1
  for (int kc = 0; kc < 2; ++kc) {
    short8 wf[9][2];
#pragma unroll
    for (int tap = 0; tap < 9; ++tap)
#pragma unroll
      for (int ct = 0; ct < 2; ++ct)
        wf[tap][ct] = __builtin_bit_cast(
            short8, wp4[((tap * 4 + (ow * 2 + ct)) * 2 + kc) * 64 + lane]);
#pragma unroll
    for (int pt = 0; pt < 2; ++pt) {
#pragma unroll
      for (int ir = 0; ir < 4; ++ir) {
#pragma unroll
        for (int kx = 0; kx < 3; ++kx) {
          int col = ch2 * 32 + pt * 16 + l15 + kx;
          short8 xf = __builtin_bit_cast(
              short8, lds[(ir * 66 + col) * 8 + ((kc * 4 + quad) ^ (col & 7))]);
          if (ir <= 2) {
#pragma unroll
            for (int ct = 0; ct < 2; ++ct)
              acc[pt][0][ct] = MFMA_BF16(wf[ir * 3 + kx][ct], xf, acc[pt][0][ct], 0, 0, 0);
          }
          if (ir >= 1) {
#pragma unroll
            for (int ct = 0; ct < 2; ++ct)
              acc[pt][1][ct] = MFMA_BF16(wf[(ir - 1) * 3 + kx][ct], xf, acc[pt][1][ct], 0, 0, 0);
          }
        }
      }
    }
  }

  uint2* c2u = (uint2*)c2;
#pragma unroll
  for (int pt = 0; pt < 2; ++pt) {
    int px = colBase + ch2 * 32 + pt * 16 + l15;
#pragma unroll
    for (int rr = 0; rr < 2; ++rr) {
      int r = r0 + rr;
      if (r > 255) continue;
#pragma unroll
      for (int ct = 0; ct < 2; ++ct) {
        f32x4 A = acc[pt][rr][ct];
        int og = (ow * 2 + ct) * 4 + quad;
        unsigned short h0 = f2bf(A[0]), h1 = f2bf(A[1]), h2 = f2bf(A[2]), h3 = f2bf(A[3]);
        uint2 val = make_uint2((unsigned)h0 | ((unsigned)h1 << 16),
                               (unsigned)h2 | ((unsigned)h3 << 16));
        c2u[(size_t)((b * 16 + og) * C2R + (r + 1)) * WW + px] = val;
      }
    }
  }
}

// ---------------------------------------------------------------------------
// k_final: out rows y0, y0+1. Round-0 tile (33.8 KB, 1 barrier).
// Interior blocks (tr in [1,126]) stage via global_load_lds dwordx4 with the
// XOR swizzle moved to the SOURCE address (LDS dest is idx-linear; 528=66*8
// so slot (rr*66+col)*8+ch == idx). Boundary blocks keep the register path
// for zero-fill. LDS contents identical both ways (XOR is an involution).
// Epilogue s-loads hoisted to kernel start.
// ---------------------------------------------------------------------------
__global__ __launch_bounds__(256, 4) void k_final(const unsigned short* __restrict__ xn,
                                                  const unsigned short* __restrict__ Wp,
                                                  const float* __restrict__ s,
                                                  const unsigned short* __restrict__ c2,
                                                  float* __restrict__ out) {
  __shared__ uint4 lds[2112];
  const int t = threadIdx.x;
  const int ctile = blockIdx.x & 3, tr = blockIdx.x >> 2;
  const int b = blockIdx.y;
  const int y0 = tr * 2;
  const int colBase = ctile * 64;

  const int lane = t & 63, w = t >> 6;
  const int ow = w & 1, ch2 = w >> 1;
  const int quad = lane >> 4, l15 = lane & 15;
  const uint4* src4 = (const uint4*)xn;
  const uint4* wp4 = (const uint4*)Wp;

  // hoisted epilogue s-loads: issue before staging, consumed after MFMA
  float sv_e[2][2];
#pragma unroll
  for (int pt = 0; pt < 2; ++pt)
#pragma unroll
    for (int rr = 0; rr < 2; ++rr)
      sv_e[pt][rr] =
          s[(b * HH + (y0 + rr)) * WW + (colBase + ch2 * 32 + pt * 16 + l15)];

  if (tr > 0 && tr < 127) {
    // fast path: 9 async direct-to-LDS loads per thread, all in flight
#pragma unroll
    for (int i = 0; i < 8; ++i) {
      int idx = i * 256 + t;
      int rr_ = idx / 528, rem = idx % 528;
      int col_ = rem >> 3, ch_ = rem & 7;
      int xrow = y0 - 1 + rr_;  // in [1,254], always valid here
      size_t srcIdx =
          ((size_t)(b * HH + xrow) * WP + colBase + col_) * 8 + (ch_ ^ (col_ & 7));
      __builtin_amdgcn_global_load_lds((gptr_t*)(const void*)(src4 + srcIdx),
                                       (lptr_t*)(void*)&lds[i * 256 + (t & 192)],
                                       16, 0, 0);
    }
    if (t < 64) {  // wave-uniform tail: elements 2048..2111
      int idx = 2048 + t;
      int rr_ = idx / 528, rem = idx % 528;
      int col_ = rem >> 3, ch_ = rem & 7;
      int xrow = y0 - 1 + rr_;
      size_t srcIdx =
          ((size_t)(b * HH + xrow) * WP + colBase + col_) * 8 + (ch_ ^ (col_ & 7));
      __builtin_amdgcn_global_load_lds((gptr_t*)(const void*)(src4 + srcIdx),
                                       (lptr_t*)(void*)&lds[2048],
                                       16, 0, 0);
    }
  } else {
    // boundary path: register staging with zero-fill (round-0 verbatim)
#pragma unroll
    for (int i = 0; i < 9; ++i) {
      int idx = i * 256 + t;
      if (idx < 2112) {
        int rr_ = idx / 528, rem = idx % 528;
        int col_ = rem >> 3, ch_ = rem & 7;
        int xrow = y0 - 1 + rr_;  // rows y0-1 .. y0+2
        uint4 v = make_uint4(0, 0, 0, 0);
        if (xrow >= 0 && xrow < HH)
          v = src4[((size_t)(b * HH + xrow) * WP + colBase + col_) * 8 + ch_];
        lds[(rr_ * 66 + col_) * 8 + (ch_ ^ (col_ & 7))] = v;
      }
    }
  }
  __syncthreads();

  f32x4 acc[2][2][2];
#pragma unroll
  for (int pt = 0; pt < 2; ++pt)
#pragma unroll
    for (int rr = 0; rr < 2; ++rr)
#pragma unroll
      for (int ct = 0; ct < 2; ++ct) acc[pt][rr][ct] = {0.f, 0.f, 0.f, 0.f};

#pragma unroll 1
  for (int kc = 0; kc < 2; ++kc) {
    short8 wf[9][2];
#pragma unroll
    for (int tap = 0; tap < 9; ++tap)
#pragma unroll
      for (int ct = 0; ct < 2; ++ct)
        wf[tap][ct] = __builtin_bit_cast(
            short8, wp4[((tap * 4 + (ow * 2 + ct)) * 2 + kc) * 64 + lane]);
#pragma unroll
    for (int pt = 0; pt < 2; ++pt) {
#pragma unroll
      for (int ir = 0; ir < 4; ++ir) {
#pragma unroll
        for (int kx = 0; kx < 3; ++kx) {
          int col = ch2 * 32 + pt * 16 + l15 + kx;
          short8 xf = __builtin_bit_cast(
              short8, lds[(ir * 66 + col) * 8 + ((kc * 4 + quad) ^ (col & 7))]);
          if (ir <= 2) {
#pragma unroll
            for (int ct = 0; ct < 2; ++ct)
              acc[pt][0][ct] = MFMA_BF16(wf[ir * 3 + kx][ct], xf, acc[pt][0][ct], 0, 0, 0);
          }
          if (ir >= 1) {
#pragma unroll
            for (int ct = 0; ct < 2; ++ct)
              acc[pt][1][ct] = MFMA_BF16(wf[(ir - 1) * 3 + kx][ct], xf, acc[pt][1][ct], 0, 0, 0);
          }
        }
      }
    }
  }

  const uint2* c2u = (const uint2*)c2;
#pragma unroll
  for (int pt = 0; pt < 2; ++pt) {
    int px = colBase + ch2 * 32 + pt * 16 + l15;
#pragma unroll
    for (int rr = 0; rr < 2; ++rr) {
      int y = y0 + rr;
      float sv = sv_e[pt][rr];
      float ys = (float)y - sv;
      float fy = floorf(ys);
      float wfr = ys - fy;
      int i0 = (int)fy;
      float lw0 = (i0 + 1 >= 0 && i0 + 1 <= HH) ? 1.0f - wfr : 0.0f;
      float lw1 = (i0 + 2 >= 0 && i0 + 2 <= HH) ? wfr : 0.0f;
      int a0 = min(max(i0 + 1, 0), HH);
      int a1 = min(max(i0 + 2, 0), HH);
#pragma unroll
      for (int ct = 0; ct < 2; ++ct) {
        f32x4 A = acc[pt][rr][ct];
        int og = (ow * 2 + ct) * 4 + quad;
        U16x4 v0, v1;
        v0.v = c2u[(size_t)((b * 16 + og) * C2R + a0) * WW + px];
        v1.v = c2u[(size_t)((b * 16 + og) * C2R + a1) * WW + px];
#pragma unroll
        for (int reg = 0; reg < 4; ++reg) {
          float lower = lw0 * bf2f(v0.h[reg]) + lw1 * bf2f(v1.h[reg]);
          out[((size_t)(b * CC + og * 4 + reg) * HH + y) * WW + px] =
              fminf(A[reg], lower);
        }
      }
    }
  }
}

// ---------------------------------------------------------------------------
extern "C" void kernel_launch(void* const* d_in, const int* in_sizes, int n_in,
                              void* d_out, int out_size, void* d_ws, size_t ws_size,
                              hipStream_t stream) {
  const float* x = (const float*)d_in[0];
  const float* Wt = (const float*)d_in[1];
  float* out = (float*)d_out;

  char* ws = (char*)d_ws;
  float* s = (float*)ws;                                   //   1,048,576 B
  unsigned short* Wp = (unsigned short*)(ws + 1048576);    //      73,728 B
  unsigned short* xn = (unsigned short*)(ws + 1122304);    //  33,816,576 B
  unsigned short* c2 = (unsigned short*)(ws + 34938880);   //  33,685,504 B
                                                           // total 68.6 MB
  k_pack<<<dim3(HH * 2, BB), 256, 0, stream>>>(x, Wt, s, xn, Wp);
  k_lower<<<dim3(4 * 129, BB), 256, 0, stream>>>(xn, Wp, s, c2);
  k_final<<<dim3(4 * 128, BB), 256, 0, stream>>>(xn, Wp, s, c2, out);
}